// Round 8
// baseline (219.048 us; speedup 1.0000x reference)
//
#include <hip/hip_runtime.h>

// LTLIF(tau=2, decay_input=False, hard reset) -> Linear -> BN, x2 blocks, +skip.
// T=128, B=256, C=512. GEMMs: M=T*B=32768, K=N=512.
//
// Round 8: exact i8-limb GEMM (4 limbs @2^32, i32 accum exact, f64 combine).
// R4/R6/R7 all ~85us @ MfmaUtil 15% across three schedules -> common defect:
// the HIP waitcnt pass sees global_load_lds as outstanding VMEM writing LDS
// and inserts its own s_waitcnt vmcnt(0) before any compiler-visible ds_read
// that may alias (can't disambiguate Bb[cur]/Bb[cur^1]) -> the hand-counted
// vmcnt(8) was nullified, prefetch drained every K-step (m233 2-phase stall).
// Fix (HK's pattern): ds_read_b128 via INLINE ASM (invisible to the waitcnt
// pass) + manual lgkmcnt(0) + sched_barrier(0) before MFMAs (rule #18).
// A streams L2->reg with 1-iter prefetch; B dbuf LDS, XOR-swizzled (0 confl).

typedef int i32x4 __attribute__((ext_vector_type(4)));

#define T_STEPS 128
#define BATCH   256
#define CH      512
#define BC      (BATCH * CH)        // 131072
#define MROWS   (T_STEPS * BATCH)   // 32768

// ---------------- async global->LDS (16B per lane, wave-uniform LDS base) ----
__device__ __forceinline__ void llds16(const void* g, void* l) {
  __builtin_amdgcn_global_load_lds(
      (const __attribute__((address_space(1))) void*)g,
      (__attribute__((address_space(3))) void*)l, 16, 0, 0);
}

// LDS byte offset of a __shared__ address (AS3 offset, 32-bit)
__device__ __forceinline__ unsigned lds_off(const void* p) {
  return (unsigned)(size_t)(__attribute__((address_space(3))) const void*)p;
}

// raw ds_read_b128: invisible to the compiler's waitcnt pass (the point!)
__device__ __forceinline__ i32x4 ds128(unsigned off) {
  i32x4 r;
  asm volatile("ds_read_b128 %0, %1" : "=v"(r) : "v"(off));
  return r;
}

// ---------------- W f32 -> 4 signed i8 limb planes (fixed point, scale 2^32) -
__global__ __launch_bounds__(256) void k_convw(const float* __restrict__ W0,
                                               const float* __restrict__ W1,
                                               signed char* __restrict__ WL0,
                                               signed char* __restrict__ WL1) {
  int b = blockIdx.x;                       // 2048 blocks: 1024 per matrix
  const float* W = (b < 1024) ? W0 : W1;
  signed char* WL = (b < 1024) ? WL0 : WL1;
  int i = (b & 1023) * 256 + threadIdx.x;   // 262144
  double z = (double)W[i] * 4294967296.0;
  z = fmin(fmax(z, -2147483647.0), 2147483647.0);  // safety clamp (never hit)
  int q = (int)llrint(z);
  int r = q;
  signed char l0 = (signed char)r; r = (r - l0) >> 8;
  signed char l1 = (signed char)r; r = (r - l1) >> 8;
  signed char l2 = (signed char)r; r = (r - l2) >> 8;
  signed char l3 = (signed char)r;
  WL[i]          = l0;
  WL[i + 262144] = l1;
  WL[i + 524288] = l2;
  WL[i + 786432] = l3;
}

// ---------------- LIF scan, block 1: x -> spikes (f32, bit-exact) -----------
__global__ __launch_bounds__(64) void k_lif1(const float* __restrict__ X,
                                             const float* __restrict__ wp,
                                             signed char* __restrict__ S) {
  int i = blockIdx.x * 64 + threadIdx.x;    // 0..BC-1
  float om = 1.0f - 1.0f / (1.0f + expf(-wp[0]));   // 0.5 exact
  float v = 0.0f;
  #pragma unroll 8
  for (int t = 0; t < T_STEPS; ++t) {
    float xt = X[(size_t)t * BC + i];
    v = v * om + xt;
    bool sp = (v >= 1.0f);
    S[(size_t)t * BC + i] = sp;
    v = sp ? 0.0f : v;
  }
}

// ---------------- LIF scan, block 2: h = f32(f64(y)*a+b) -> spikes ----------
__global__ __launch_bounds__(64) void k_lif2(const float* __restrict__ Y,
                                             const double* __restrict__ sA,
                                             const double* __restrict__ sB,
                                             const float* __restrict__ wp,
                                             signed char* __restrict__ S) {
  int i = blockIdx.x * 64 + threadIdx.x;
  int c = i & (CH - 1);
  double a = sA[c], b = sB[c];
  float om = 1.0f - 1.0f / (1.0f + expf(-wp[0]));
  float v = 0.0f;
  #pragma unroll 8
  for (int t = 0; t < T_STEPS; ++t) {
    float h = (float)((double)Y[(size_t)t * BC + i] * a + b);
    v = v * om + h;
    bool sp = (v >= 1.0f);
    S[(size_t)t * BC + i] = sp;
    v = sp ? 0.0f : v;
  }
}

// ---------------- i8 limb GEMM + fused BN partial stats ----------------------
// Tile 128(M) x 64(N), BK=64, 4 waves (2Mx2N); wave tile 64x32.
// A: L2->register stream, 1-iter prefetch. B: dbuf LDS via global_load_lds,
// counted vmcnt(8) publish, ASM ds_read (waitcnt-pass-invisible), lgkmcnt(0)
// + sched_barrier fence, setprio'd MFMA cluster, bare release barrier.
__global__ __launch_bounds__(256) void k_gemm(const signed char* __restrict__ S,
                                              const signed char* __restrict__ WL,
                                              float* __restrict__ Y,
                                              double* __restrict__ sumP,
                                              double* __restrict__ sqP) {
  __shared__ __align__(16) signed char Bb[2][4][64 * 64];    // 16 KB x2

  const int tid  = threadIdx.x;
  const int wid  = tid >> 6;
  const int lane = tid & 63;
  // XCD partition: xcd = bid&7 (round-robin dispatch). Each XCD owns bm in
  // [xcd*32, xcd*32+32) -> 2 MB S slice resident in its L2, reused over bn.
  const int bid   = blockIdx.x;
  const int xcd   = bid & 7;
  const int local = bid >> 3;                  // 0..255
  const int bn    = local & 7;                 // 0..7   (N/64)
  const int bm    = xcd * 32 + (local >> 3);   // 0..255 (M/128)
  const int m0 = bm * 128, n0 = bn * 64;
  const int wm = wid >> 1, wn = wid & 1;
  const int lr = lane & 15, lg = lane >> 4;

  i32x4 acc[4][2][4] = {};   // [m-frag][n-frag][limb]

  // B stage: 4 limbs x (64 rows x 4 granules), 1 load/thread/limb
  auto STAGE = [&](int buf, int kt) {
    int row = tid >> 2, gl = tid & 3;
    int gg = gl ^ ((row >> 1) & 3);
    #pragma unroll
    for (int j = 0; j < 4; ++j)
      llds16(WL + (size_t)j * 262144 + (size_t)(n0 + row) * 512 + kt + gg * 16,
             (char*)Bb[buf][j] + wid * 1024);
  };

  // precomputed swizzled read offsets (per n-frag), relative to Bb[0][0]
  const unsigned bbase = lds_off(&Bb[0][0][0]);
  unsigned voff[2];
  #pragma unroll
  for (int n = 0; n < 2; ++n) {
    int r = wn * 32 + n * 16 + lr;
    int g = lg ^ ((r >> 1) & 3);
    voff[n] = bbase + (unsigned)(r * 64 + g * 16);
  }

  // A stream base: row (m0 + wm*64 + lr + 16m), bytes [kt + lg*16, +16)
  const signed char* aP = S + (size_t)(m0 + wm * 64 + lr) * 512 + lg * 16;
  i32x4 a[2][4];

  // prologue: stage B(0), load a(0)   [8 vmem in flight]
  STAGE(0, 0);
  #pragma unroll
  for (int m = 0; m < 4; ++m)
    a[0][m] = *(const i32x4*)(aP + m * 8192);

  #pragma unroll
  for (int i = 0; i < 8; ++i) {
    const int cur = i & 1;
    if (i < 7) {
      STAGE(cur ^ 1, (i + 1) * 64);                      // 4 vmem
      #pragma unroll
      for (int m = 0; m < 4; ++m)                        // 4 vmem (A prefetch)
        a[cur ^ 1][m] = *(const i32x4*)(aP + m * 8192 + (i + 1) * 64);
    }
    // publish: wait only the PREVIOUS stage (this iter's 8 stay in flight)
    if (i < 7) asm volatile("s_waitcnt vmcnt(8)" ::: "memory");
    else       asm volatile("s_waitcnt vmcnt(0)" ::: "memory");
    asm volatile("s_barrier" ::: "memory");

    // B fragments via asm ds_read (invisible to the waitcnt pass)
    i32x4 b[2][4];
    #pragma unroll
    for (int n = 0; n < 2; ++n)
      #pragma unroll
      for (int j = 0; j < 4; ++j)
        b[n][j] = ds128(voff[n] + (unsigned)(cur * 16384 + j * 4096));

    // rule #18: manual wait + scheduler fence before reg-only MFMAs
    asm volatile("s_waitcnt lgkmcnt(0)" ::: "memory");
    __builtin_amdgcn_sched_barrier(0);

    __builtin_amdgcn_s_setprio(1);
    #pragma unroll
    for (int j = 0; j < 4; ++j)
      #pragma unroll
      for (int m = 0; m < 4; ++m)
        #pragma unroll
        for (int n = 0; n < 2; ++n)
          acc[m][n][j] = __builtin_amdgcn_mfma_i32_16x16x64_i8(
              a[cur][m], b[n][j], acc[m][n][j], 0, 0, 0);
    __builtin_amdgcn_s_setprio(0);

    // release: our ds_reads already retired (lgkmcnt(0) above) -> bare barrier
    asm volatile("s_barrier" ::: "memory");
  }

  // ---- epilogue: exact limb combine, Y write, fused BN partials -------------
  // C/D: col = lane&15 (+16n +32wn), row = (lane>>4)*4 + q (+16m +64wm)
  const int r0 = m0 + wm * 64 + lg * 4;
  const int cl = wn * 32 + lr;               // block-local col of n=0 frag
  double s0 = 0, q0 = 0, s1 = 0, q1 = 0;
  #pragma unroll
  for (int m = 0; m < 4; ++m)
    #pragma unroll
    for (int n = 0; n < 2; ++n)
      #pragma unroll
      for (int q = 0; q < 4; ++q) {
        double yv = (((double)acc[m][n][3][q] * 256.0 + (double)acc[m][n][2][q]) * 256.0
                     + (double)acc[m][n][1][q]) * 256.0 + (double)acc[m][n][0][q];
        float yf = (float)(yv * 0x1p-32);
        Y[(size_t)(r0 + m * 16 + q) * 512 + n0 + cl + n * 16] = yf;
        double yd = (double)yf;
        if (n == 0) { s0 += yd; q0 += yd * yd; }
        else        { s1 += yd; q1 += yd * yd; }
      }
  s0 += __shfl_xor(s0, 16); s0 += __shfl_xor(s0, 32);
  q0 += __shfl_xor(q0, 16); q0 += __shfl_xor(q0, 32);
  s1 += __shfl_xor(s1, 16); s1 += __shfl_xor(s1, 32);
  q1 += __shfl_xor(q1, 16); q1 += __shfl_xor(q1, 32);

  double* shS = (double*)Bb[0][0];     // reuse LDS (dead after final barrier)
  double* shQ = shS + 128;
  __syncthreads();                     // full drain once; epilogue is cheap
  if (lane < 16) {
    shS[wm * 64 + cl]      = s0;  shQ[wm * 64 + cl]      = q0;
    shS[wm * 64 + cl + 16] = s1;  shQ[wm * 64 + cl + 16] = q1;
  }
  __syncthreads();
  if (tid < 64) {   // cross-wave (wm) add; local channel = tid; fixed order
    sumP[(size_t)(n0 + tid) * 256 + bm] = shS[tid] + shS[64 + tid];
    sqP [(size_t)(n0 + tid) * 256 + bm] = shQ[tid] + shQ[64 + tid];
  }
}

// ---------------- BN stats stage 2: per-channel a, b (tree, deterministic) --
__global__ __launch_bounds__(256) void k_stats2(const double* __restrict__ sumP,
                                                const double* __restrict__ sqP,
                                                const float* __restrict__ gamma,
                                                const float* __restrict__ beta,
                                                double* __restrict__ sA,
                                                double* __restrict__ sB) {
  __shared__ double shS[256], shQ[256];
  int c = blockIdx.x;       // 512 blocks, one channel each
  int t = threadIdx.x;      // 256 partials, coalesced
  shS[t] = sumP[(size_t)c * 256 + t];
  shQ[t] = sqP [(size_t)c * 256 + t];
  __syncthreads();
  for (int w = 128; w >= 1; w >>= 1) {
    if (t < w) { shS[t] += shS[t + w]; shQ[t] += shQ[t + w]; }
    __syncthreads();
  }
  if (t == 0) {
    const double invN = 1.0 / 32768.0;
    double mean = shS[0] * invN;
    double var  = shQ[0] * invN - mean * mean;
    double rstd = rsqrt(var + 1e-5);
    double a = (double)gamma[c] * rstd;
    sA[c] = a;
    sB[c] = (double)beta[c] - mean * a;
  }
}

// ---------------- final: out = f32(f64(y)*a + b + x) ------------------------
__global__ __launch_bounds__(256) void k_final(float* __restrict__ Y,
                                               const float* __restrict__ X,
                                               const double* __restrict__ sA,
                                               const double* __restrict__ sB) {
  size_t i = (size_t)blockIdx.x * 256 + threadIdx.x;  // float4 index
  int c0 = (int)((i * 4) & (CH - 1));
  float4 y = ((const float4*)Y)[i];
  float4 x = ((const float4*)X)[i];
  float4 o;
  o.x = (float)((double)y.x * sA[c0 + 0] + sB[c0 + 0] + (double)x.x);
  o.y = (float)((double)y.y * sA[c0 + 1] + sB[c0 + 1] + (double)x.y);
  o.z = (float)((double)y.z * sA[c0 + 2] + sB[c0 + 2] + (double)x.z);
  o.w = (float)((double)y.w * sA[c0 + 3] + sB[c0 + 3] + (double)x.w);
  ((float4*)Y)[i] = o;
}

// ---------------- launch ----------------------------------------------------
extern "C" void kernel_launch(void* const* d_in, const int* in_sizes, int n_in,
                              void* d_out, int out_size, void* d_ws, size_t ws_size,
                              hipStream_t stream) {
  (void)in_sizes; (void)n_in; (void)out_size; (void)ws_size;

  const float* x   = (const float*)d_in[0];
  const float* w0  = (const float*)d_in[1];
  const float* W0  = (const float*)d_in[2];
  // d_in[3] = b0: absorbed by BN
  const float* g0  = (const float*)d_in[4];
  const float* be0 = (const float*)d_in[5];
  const float* w1  = (const float*)d_in[6];
  const float* W1  = (const float*)d_in[7];
  // d_in[8] = b1: absorbed by BN
  const float* g1  = (const float*)d_in[9];
  const float* be1 = (const float*)d_in[10];
  float* Y = (float*)d_out;   // y1, then y2, then final output

  char* ws = (char*)d_ws;
  signed char* WL0  = (signed char*)(ws + 0x0000000);  // 1 MB (4 planes)
  signed char* WL1  = (signed char*)(ws + 0x0100000);  // 1 MB
  signed char* spk  = (signed char*)(ws + 0x0200000);  // 16.78 MB
  double*      sumP = (double*)(ws + 0x1200000);       // 1 MB [512][256]
  double*      sqP  = (double*)(ws + 0x1300000);       // 1 MB
  double*      sA   = (double*)(ws + 0x1400000);       // 4 KB
  double*      sB   = (double*)(ws + 0x1402000);       // 4 KB

  k_convw<<<2048, 256, 0, stream>>>(W0, W1, WL0, WL1);

  // block 1
  k_lif1 <<<BC / 64, 64, 0, stream>>>(x, w0, spk);
  k_gemm <<<(MROWS / 128) * (CH / 64), 256, 0, stream>>>(spk, WL0, Y, sumP, sqP);
  k_stats2<<<512, 256, 0, stream>>>(sumP, sqP, g0, be0, sA, sB);

  // block 2 (BN affine of block 1 fused into LIF input, f64->f32 once)
  k_lif2 <<<BC / 64, 64, 0, stream>>>(Y, sA, sB, w1, spk);
  k_gemm <<<(MROWS / 128) * (CH / 64), 256, 0, stream>>>(spk, WL1, Y, sumP, sqP);
  k_stats2<<<512, 256, 0, stream>>>(sumP, sqP, g1, be1, sA, sB);

  // out = BN(y2) + x
  k_final<<<(MROWS * CH) / (4 * 256), 256, 0, stream>>>(Y, x, sA, sB);
}

// Round 9
// 182.275 us; speedup vs baseline: 1.2017x; 1.2017x over previous
//
#include <hip/hip_runtime.h>

// LTLIF(tau=2, decay_input=False, hard reset) -> Linear -> BN, x2 blocks, +skip.
// T=128, B=256, C=512. GEMMs: M=T*B=32768, K=N=512.
//
// Round 9: exact i8-limb GEMM (4 limbs @2^32, i32 accum exact, f64 combine).
// R4/R6/R7/R8 all ~85us @ MfmaUtil 15% across FOUR schedules -> schedule was
// never the constraint. Unified-regfile arithmetic: acc 128 AGPR + 140 VGPR
// = 268 > 256 -> 1 wave/SIMD (occupancy counter ~10% = 4 waves/CU confirms).
// Zero TLP: every LDS/L2 latency exposed. Fix: __launch_bounds__(256,2)
// (forces total <= 256 -> 2 waves/SIMD) + drop A reg double-buffer (-16) and
// reorder the iter: A-loads first, counted vmcnt(8) publish for B-stage,
// vmcnt(4) for A after ds_read issue, lgkmcnt(0)+sched_barrier before MFMAs.
// Everything else identical to round 8 (asm ds_read, XOR swizzle, XCD map).

typedef int i32x4 __attribute__((ext_vector_type(4)));

#define T_STEPS 128
#define BATCH   256
#define CH      512
#define BC      (BATCH * CH)        // 131072
#define MROWS   (T_STEPS * BATCH)   // 32768

// ---------------- async global->LDS (16B per lane, wave-uniform LDS base) ----
__device__ __forceinline__ void llds16(const void* g, void* l) {
  __builtin_amdgcn_global_load_lds(
      (const __attribute__((address_space(1))) void*)g,
      (__attribute__((address_space(3))) void*)l, 16, 0, 0);
}

// LDS byte offset of a __shared__ address (AS3 offset, 32-bit)
__device__ __forceinline__ unsigned lds_off(const void* p) {
  return (unsigned)(size_t)(__attribute__((address_space(3))) const void*)p;
}

// raw ds_read_b128: invisible to the compiler's waitcnt pass
__device__ __forceinline__ i32x4 ds128(unsigned off) {
  i32x4 r;
  asm volatile("ds_read_b128 %0, %1" : "=v"(r) : "v"(off));
  return r;
}

// ---------------- W f32 -> 4 signed i8 limb planes (fixed point, scale 2^32) -
__global__ __launch_bounds__(256) void k_convw(const float* __restrict__ W0,
                                               const float* __restrict__ W1,
                                               signed char* __restrict__ WL0,
                                               signed char* __restrict__ WL1) {
  int b = blockIdx.x;                       // 2048 blocks: 1024 per matrix
  const float* W = (b < 1024) ? W0 : W1;
  signed char* WL = (b < 1024) ? WL0 : WL1;
  int i = (b & 1023) * 256 + threadIdx.x;   // 262144
  double z = (double)W[i] * 4294967296.0;
  z = fmin(fmax(z, -2147483647.0), 2147483647.0);  // safety clamp (never hit)
  int q = (int)llrint(z);
  int r = q;
  signed char l0 = (signed char)r; r = (r - l0) >> 8;
  signed char l1 = (signed char)r; r = (r - l1) >> 8;
  signed char l2 = (signed char)r; r = (r - l2) >> 8;
  signed char l3 = (signed char)r;
  WL[i]          = l0;
  WL[i + 262144] = l1;
  WL[i + 524288] = l2;
  WL[i + 786432] = l3;
}

// ---------------- LIF scan, block 1: x -> spikes (f32, bit-exact) -----------
__global__ __launch_bounds__(64) void k_lif1(const float* __restrict__ X,
                                             const float* __restrict__ wp,
                                             signed char* __restrict__ S) {
  int i = blockIdx.x * 64 + threadIdx.x;    // 0..BC-1
  float om = 1.0f - 1.0f / (1.0f + expf(-wp[0]));   // 0.5 exact
  float v = 0.0f;
  #pragma unroll 8
  for (int t = 0; t < T_STEPS; ++t) {
    float xt = X[(size_t)t * BC + i];
    v = v * om + xt;
    bool sp = (v >= 1.0f);
    S[(size_t)t * BC + i] = sp;
    v = sp ? 0.0f : v;
  }
}

// ---------------- LIF scan, block 2: h = f32(f64(y)*a+b) -> spikes ----------
__global__ __launch_bounds__(64) void k_lif2(const float* __restrict__ Y,
                                             const double* __restrict__ sA,
                                             const double* __restrict__ sB,
                                             const float* __restrict__ wp,
                                             signed char* __restrict__ S) {
  int i = blockIdx.x * 64 + threadIdx.x;
  int c = i & (CH - 1);
  double a = sA[c], b = sB[c];
  float om = 1.0f - 1.0f / (1.0f + expf(-wp[0]));
  float v = 0.0f;
  #pragma unroll 8
  for (int t = 0; t < T_STEPS; ++t) {
    float h = (float)((double)Y[(size_t)t * BC + i] * a + b);
    v = v * om + h;
    bool sp = (v >= 1.0f);
    S[(size_t)t * BC + i] = sp;
    v = sp ? 0.0f : v;
  }
}

// ---------------- i8 limb GEMM + fused BN partial stats ----------------------
// Tile 128(M) x 64(N), BK=64, 4 waves (2Mx2N); wave tile 64x32.
// A: L2->register (single-buffered, loads at iter top). B: dbuf LDS via
// global_load_lds, counted vmcnt publish, ASM ds_read, lgkmcnt(0)+sched
// fence, setprio'd MFMA cluster. __launch_bounds__(256,2) -> 2 waves/SIMD.
__global__ __launch_bounds__(256, 2) void k_gemm(const signed char* __restrict__ S,
                                                 const signed char* __restrict__ WL,
                                                 float* __restrict__ Y,
                                                 double* __restrict__ sumP,
                                                 double* __restrict__ sqP) {
  __shared__ __align__(16) signed char Bb[2][4][64 * 64];    // 16 KB x2

  const int tid  = threadIdx.x;
  const int wid  = tid >> 6;
  const int lane = tid & 63;
  // XCD partition: xcd = bid&7 (round-robin dispatch). Each XCD owns bm in
  // [xcd*32, xcd*32+32) -> 2 MB S slice resident in its L2, reused over bn.
  const int bid   = blockIdx.x;
  const int xcd   = bid & 7;
  const int local = bid >> 3;                  // 0..255
  const int bn    = local & 7;                 // 0..7   (N/64)
  const int bm    = xcd * 32 + (local >> 3);   // 0..255 (M/128)
  const int m0 = bm * 128, n0 = bn * 64;
  const int wm = wid >> 1, wn = wid & 1;
  const int lr = lane & 15, lg = lane >> 4;

  i32x4 acc[4][2][4] = {};   // [m-frag][n-frag][limb] = 128 regs

  // B stage: 4 limbs x (64 rows x 4 granules), 1 load/thread/limb
  auto STAGE = [&](int buf, int kt) {
    int row = tid >> 2, gl = tid & 3;
    int gg = gl ^ ((row >> 1) & 3);
    #pragma unroll
    for (int j = 0; j < 4; ++j)
      llds16(WL + (size_t)j * 262144 + (size_t)(n0 + row) * 512 + kt + gg * 16,
             (char*)Bb[buf][j] + wid * 1024);
  };

  // precomputed swizzled read offsets (per n-frag), relative to Bb[0][0]
  const unsigned bbase = lds_off(&Bb[0][0][0]);
  unsigned voff[2];
  #pragma unroll
  for (int n = 0; n < 2; ++n) {
    int r = wn * 32 + n * 16 + lr;
    int g = lg ^ ((r >> 1) & 3);
    voff[n] = bbase + (unsigned)(r * 64 + g * 16);
  }

  // A stream base: row (m0 + wm*64 + lr + 16m), bytes [kt + lg*16, +16)
  const signed char* aP = S + (size_t)(m0 + wm * 64 + lr) * 512 + lg * 16;

  STAGE(0, 0);                 // prologue: 4 vmem in flight

  #pragma unroll
  for (int i = 0; i < 8; ++i) {
    const int cur = i & 1;

    // A(cur) loads (4 vmem) — needed this iter, issue first
    i32x4 a[4];
    #pragma unroll
    for (int m = 0; m < 4; ++m)
      a[m] = *(const i32x4*)(aP + m * 8192 + i * 64);

    if (i < 7) STAGE(cur ^ 1, (i + 1) * 64);             // +4 vmem (next B)

    // publish B(cur): wait the oldest 4 (stage cur), leave A + stage(next)
    if (i < 7) asm volatile("s_waitcnt vmcnt(8)" ::: "memory");
    else       asm volatile("s_waitcnt vmcnt(4)" ::: "memory");
    asm volatile("s_barrier" ::: "memory");

    // B fragments via asm ds_read (invisible to the waitcnt pass)
    i32x4 b[2][4];
    #pragma unroll
    for (int n = 0; n < 2; ++n)
      #pragma unroll
      for (int j = 0; j < 4; ++j)
        b[n][j] = ds128(voff[n] + (unsigned)(cur * 16384 + j * 4096));

    // A done (stage(next) stays in flight), ds_reads done, fence, compute
    if (i < 7) asm volatile("s_waitcnt vmcnt(4)" ::: "memory");
    else       asm volatile("s_waitcnt vmcnt(0)" ::: "memory");
    asm volatile("s_waitcnt lgkmcnt(0)" ::: "memory");
    __builtin_amdgcn_sched_barrier(0);

    __builtin_amdgcn_s_setprio(1);
    #pragma unroll
    for (int j = 0; j < 4; ++j)
      #pragma unroll
      for (int m = 0; m < 4; ++m)
        #pragma unroll
        for (int n = 0; n < 2; ++n)
          acc[m][n][j] = __builtin_amdgcn_mfma_i32_16x16x64_i8(
              a[m], b[n][j], acc[m][n][j], 0, 0, 0);
    __builtin_amdgcn_s_setprio(0);

    // release: our ds_reads already retired (lgkmcnt(0)) -> bare barrier
    asm volatile("s_barrier" ::: "memory");
  }

  // ---- epilogue: exact limb combine, Y write, fused BN partials -------------
  // C/D: col = lane&15 (+16n +32wn), row = (lane>>4)*4 + q (+16m +64wm)
  const int r0 = m0 + wm * 64 + lg * 4;
  const int cl = wn * 32 + lr;               // block-local col of n=0 frag
  double s0 = 0, q0 = 0, s1 = 0, q1 = 0;
  #pragma unroll
  for (int m = 0; m < 4; ++m)
    #pragma unroll
    for (int n = 0; n < 2; ++n)
      #pragma unroll
      for (int q = 0; q < 4; ++q) {
        double yv = (((double)acc[m][n][3][q] * 256.0 + (double)acc[m][n][2][q]) * 256.0
                     + (double)acc[m][n][1][q]) * 256.0 + (double)acc[m][n][0][q];
        float yf = (float)(yv * 0x1p-32);
        Y[(size_t)(r0 + m * 16 + q) * 512 + n0 + cl + n * 16] = yf;
        double yd = (double)yf;
        if (n == 0) { s0 += yd; q0 += yd * yd; }
        else        { s1 += yd; q1 += yd * yd; }
      }
  s0 += __shfl_xor(s0, 16); s0 += __shfl_xor(s0, 32);
  q0 += __shfl_xor(q0, 16); q0 += __shfl_xor(q0, 32);
  s1 += __shfl_xor(s1, 16); s1 += __shfl_xor(s1, 32);
  q1 += __shfl_xor(q1, 16); q1 += __shfl_xor(q1, 32);

  double* shS = (double*)Bb[0][0];     // reuse LDS (dead after final barrier)
  double* shQ = shS + 128;
  __syncthreads();                     // full drain once; epilogue is cheap
  if (lane < 16) {
    shS[wm * 64 + cl]      = s0;  shQ[wm * 64 + cl]      = q0;
    shS[wm * 64 + cl + 16] = s1;  shQ[wm * 64 + cl + 16] = q1;
  }
  __syncthreads();
  if (tid < 64) {   // cross-wave (wm) add; local channel = tid; fixed order
    sumP[(size_t)(n0 + tid) * 256 + bm] = shS[tid] + shS[64 + tid];
    sqP [(size_t)(n0 + tid) * 256 + bm] = shQ[tid] + shQ[64 + tid];
  }
}

// ---------------- BN stats stage 2: per-channel a, b (tree, deterministic) --
__global__ __launch_bounds__(256) void k_stats2(const double* __restrict__ sumP,
                                                const double* __restrict__ sqP,
                                                const float* __restrict__ gamma,
                                                const float* __restrict__ beta,
                                                double* __restrict__ sA,
                                                double* __restrict__ sB) {
  __shared__ double shS[256], shQ[256];
  int c = blockIdx.x;       // 512 blocks, one channel each
  int t = threadIdx.x;      // 256 partials, coalesced
  shS[t] = sumP[(size_t)c * 256 + t];
  shQ[t] = sqP [(size_t)c * 256 + t];
  __syncthreads();
  for (int w = 128; w >= 1; w >>= 1) {
    if (t < w) { shS[t] += shS[t + w]; shQ[t] += shQ[t + w]; }
    __syncthreads();
  }
  if (t == 0) {
    const double invN = 1.0 / 32768.0;
    double mean = shS[0] * invN;
    double var  = shQ[0] * invN - mean * mean;
    double rstd = rsqrt(var + 1e-5);
    double a = (double)gamma[c] * rstd;
    sA[c] = a;
    sB[c] = (double)beta[c] - mean * a;
  }
}

// ---------------- final: out = f32(f64(y)*a + b + x) ------------------------
__global__ __launch_bounds__(256) void k_final(float* __restrict__ Y,
                                               const float* __restrict__ X,
                                               const double* __restrict__ sA,
                                               const double* __restrict__ sB) {
  size_t i = (size_t)blockIdx.x * 256 + threadIdx.x;  // float4 index
  int c0 = (int)((i * 4) & (CH - 1));
  float4 y = ((const float4*)Y)[i];
  float4 x = ((const float4*)X)[i];
  float4 o;
  o.x = (float)((double)y.x * sA[c0 + 0] + sB[c0 + 0] + (double)x.x);
  o.y = (float)((double)y.y * sA[c0 + 1] + sB[c0 + 1] + (double)x.y);
  o.z = (float)((double)y.z * sA[c0 + 2] + sB[c0 + 2] + (double)x.z);
  o.w = (float)((double)y.w * sA[c0 + 3] + sB[c0 + 3] + (double)x.w);
  ((float4*)Y)[i] = o;
}

// ---------------- launch ----------------------------------------------------
extern "C" void kernel_launch(void* const* d_in, const int* in_sizes, int n_in,
                              void* d_out, int out_size, void* d_ws, size_t ws_size,
                              hipStream_t stream) {
  (void)in_sizes; (void)n_in; (void)out_size; (void)ws_size;

  const float* x   = (const float*)d_in[0];
  const float* w0  = (const float*)d_in[1];
  const float* W0  = (const float*)d_in[2];
  // d_in[3] = b0: absorbed by BN
  const float* g0  = (const float*)d_in[4];
  const float* be0 = (const float*)d_in[5];
  const float* w1  = (const float*)d_in[6];
  const float* W1  = (const float*)d_in[7];
  // d_in[8] = b1: absorbed by BN
  const float* g1  = (const float*)d_in[9];
  const float* be1 = (const float*)d_in[10];
  float* Y = (float*)d_out;   // y1, then y2, then final output

  char* ws = (char*)d_ws;
  signed char* WL0  = (signed char*)(ws + 0x0000000);  // 1 MB (4 planes)
  signed char* WL1  = (signed char*)(ws + 0x0100000);  // 1 MB
  signed char* spk  = (signed char*)(ws + 0x0200000);  // 16.78 MB
  double*      sumP = (double*)(ws + 0x1200000);       // 1 MB [512][256]
  double*      sqP  = (double*)(ws + 0x1300000);       // 1 MB
  double*      sA   = (double*)(ws + 0x1400000);       // 4 KB
  double*      sB   = (double*)(ws + 0x1402000);       // 4 KB

  k_convw<<<2048, 256, 0, stream>>>(W0, W1, WL0, WL1);

  // block 1
  k_lif1 <<<BC / 64, 64, 0, stream>>>(x, w0, spk);
  k_gemm <<<(MROWS / 128) * (CH / 64), 256, 0, stream>>>(spk, WL0, Y, sumP, sqP);
  k_stats2<<<512, 256, 0, stream>>>(sumP, sqP, g0, be0, sA, sB);

  // block 2 (BN affine of block 1 fused into LIF input, f64->f32 once)
  k_lif2 <<<BC / 64, 64, 0, stream>>>(Y, sA, sB, w1, spk);
  k_gemm <<<(MROWS / 128) * (CH / 64), 256, 0, stream>>>(spk, WL1, Y, sumP, sqP);
  k_stats2<<<512, 256, 0, stream>>>(sumP, sqP, g1, be1, sA, sB);

  // out = BN(y2) + x
  k_final<<<(MROWS * CH) / (4 * 256), 256, 0, stream>>>(Y, x, sA, sB);
}